// Round 5
// baseline (465.465 us; speedup 1.0000x reference)
//
#include <hip/hip_runtime.h>
#include <hip/hip_bf16.h>

// CoarseGraining: y[i,b] = heg[b] * sum_j exp(-beta[j,b] * d2(i,j)) * wrho[j]
// N = M = 8192, NB = 16, WIDTH = 32.
// Inputs: float32 (R1 evidence: bf16-cast reads gave NaN via powf(neg)).
// OUTPUT: float32 (reference returns f32; R2-R4 wrote bf16 and produced
//   error == exactly max|ref| — the signature of a half-filled f32 buffer
//   with nonnegative ref). A runtime input-encoding probe is kept as
//   insurance.
// WS budget: 1.1253 MB layout proven mapped in R1.

#define N_PTS 8192
#define M_PTS 8192
#define NBASIS 16
#define WIDTH 32
#define TI 256      // i-points per block in pair kernel (== blockDim.x)
#define JC 256      // j-points per block (j-chunk)

typedef unsigned short ushort_t;

__device__ __forceinline__ float bfbits2f(ushort_t u) {
    unsigned int v = ((unsigned int)u) << 16;
    return __uint_as_float(v);
}

// Read element i of buffer p, which holds either float32 or bf16 values.
__device__ __forceinline__ float ldv(const void* p, int i, bool isf32) {
    if (isf32) return ((const float*)p)[i];
    return bfbits2f(((const ushort_t*)p)[i]);
}

__device__ __forceinline__ float log_cosh_f(float x) {
    float a = fabsf(x);
    // log(cosh(x)) = |x| + log1p(exp(-2|x|)) - log(2)
    return a + log1pf(__expf(-2.0f * a)) - 0.6931471805599453f;
}

// ---------------- Stage 1: decode inputs + per-source-point quantities ----
// cw[j]           = (cx, cy, cz, wrho)
// betaneg[j*16+b] = -log2(e) * beta[j,b]  (so exp(-beta*d2) = exp2(bn*d2))
// hegf[0..15]     = log_cosh(embed(0))^1.5 ; hegf[16] = isf32 flag
__global__ __launch_bounds__(256)
void cg_prep(const void* __restrict__ rho,
             const void* __restrict__ gamma,
             const void* __restrict__ coords,
             const void* __restrict__ weights,
             const void* __restrict__ w1,
             const void* __restrict__ b1,
             const void* __restrict__ w2,
             const void* __restrict__ b2,
             float4* __restrict__ cw,
             float* __restrict__ betaneg,
             float* __restrict__ hegf)
{
    const float PI_F = 3.14159265358979323846f;
    const float LOG2E = 1.4426950408889634f;

    // --- runtime dtype detection (uniform across all threads) ---
    // rho lies in [0.05, 2.0]. If data is bf16, EVEN-index u16 halfwords are
    // real rho values -> decode into range. If f32, they are low-mantissa
    // noise -> almost never in range.
    const ushort_t* ru = (const ushort_t*)rho;
    int cnt = 0;
    #pragma unroll
    for (int k = 0; k < 32; ++k) {
        float v = bfbits2f(ru[2 * k]);
        if (v >= 0.03f && v <= 2.2f) cnt++;
    }
    const bool isf32 = (cnt < 16);

    int j = blockIdx.x * blockDim.x + threadIdx.x;

    if (j < N_PTS) {
        float r = ldv(rho, j, isf32);
        float g = ldv(gamma, j, isf32);
        float c83 = 4.0f * powf(3.0f * PI_F * PI_F, 2.0f / 3.0f);   // 38.2831
        float s2 = g / (c83 * powf(r, 8.0f / 3.0f));
        float x = logf(s2 + 1e-4f);

        float emb[NBASIS];
        #pragma unroll
        for (int b = 0; b < NBASIS; ++b) emb[b] = ldv(b2, b, isf32);
        for (int w = 0; w < WIDTH; ++w) {
            float h = tanhf(fmaf(x, ldv(w1, w, isf32), ldv(b1, w, isf32)));
            #pragma unroll
            for (int b = 0; b < NBASIS; ++b)
                emb[b] = fmaf(h, ldv(w2, w * NBASIS + b, isf32), emb[b]);
        }
        float pref = PI_F * powf(0.5f * r, 2.0f / 3.0f);
        #pragma unroll
        for (int b = 0; b < NBASIS; ++b)
            betaneg[j * NBASIS + b] = -LOG2E * pref * log_cosh_f(emb[b]);

        cw[j] = make_float4(ldv(coords, j * 3 + 0, isf32),
                            ldv(coords, j * 3 + 1, isf32),
                            ldv(coords, j * 3 + 2, isf32),
                            ldv(weights, j, isf32) * r);
    }

    if (blockIdx.x == 0 && threadIdx.x == 0) {
        // heg_scale = log_cosh(field_embed(0))^1.5
        float emb0[NBASIS];
        #pragma unroll
        for (int b = 0; b < NBASIS; ++b) emb0[b] = ldv(b2, b, isf32);
        for (int w = 0; w < WIDTH; ++w) {
            float h = tanhf(ldv(b1, w, isf32));   // x = 0
            #pragma unroll
            for (int b = 0; b < NBASIS; ++b)
                emb0[b] = fmaf(h, ldv(w2, w * NBASIS + b, isf32), emb0[b]);
        }
        #pragma unroll
        for (int b = 0; b < NBASIS; ++b) {
            float lc = fmaxf(log_cosh_f(emb0[b]), 0.0f);   // guard FP -0-eps
            hegf[b] = powf(lc, 1.5f);
        }
        hegf[NBASIS] = isf32 ? 1.0f : 0.0f;
    }
}

// ---------------- Stage 2: all-pairs accumulation ----------------
// grid = (M/TI, N/JC); each thread owns one i over one j-chunk, 16 fp32 accs.
__global__ __launch_bounds__(256)
void cg_pairs(const void* __restrict__ out_coords,
              const float4* __restrict__ cw,
              const float* __restrict__ betaneg,
              const float* __restrict__ hegf,
              float* __restrict__ ypart)
{
    const bool isf32 = (hegf[NBASIS] > 0.5f);   // wave-uniform
    int i = blockIdx.x * TI + threadIdx.x;
    float ox = ldv(out_coords, i * 3 + 0, isf32);
    float oy = ldv(out_coords, i * 3 + 1, isf32);
    float oz = ldv(out_coords, i * 3 + 2, isf32);

    float acc[NBASIS];
    #pragma unroll
    for (int b = 0; b < NBASIS; ++b) acc[b] = 0.0f;

    int j0 = blockIdx.y * JC;
    for (int j = j0; j < j0 + JC; ++j) {
        float4 c = cw[j];                    // wave-uniform load
        float dx = ox - c.x;
        float dy = oy - c.y;
        float dz = oz - c.z;
        float d2 = fmaf(dx, dx, fmaf(dy, dy, dz * dz));
        const float4* bn = (const float4*)&betaneg[j * NBASIS];  // uniform, 64 B
        #pragma unroll
        for (int q = 0; q < NBASIS / 4; ++q) {
            float4 b4 = bn[q];
            float e0 = __builtin_amdgcn_exp2f(b4.x * d2);
            float e1 = __builtin_amdgcn_exp2f(b4.y * d2);
            float e2 = __builtin_amdgcn_exp2f(b4.z * d2);
            float e3 = __builtin_amdgcn_exp2f(b4.w * d2);
            acc[q * 4 + 0] = fmaf(e0, c.w, acc[q * 4 + 0]);
            acc[q * 4 + 1] = fmaf(e1, c.w, acc[q * 4 + 1]);
            acc[q * 4 + 2] = fmaf(e2, c.w, acc[q * 4 + 2]);
            acc[q * 4 + 3] = fmaf(e3, c.w, acc[q * 4 + 3]);
        }
    }
    #pragma unroll
    for (int b = 0; b < NBASIS; ++b)
        atomicAdd(&ypart[i * NBASIS + b], acc[b]);
}

// ---------------- Stage 3: scale, FLOAT32 output ----------------
__global__ __launch_bounds__(256)
void cg_finalize(const float* __restrict__ ypart,
                 const float* __restrict__ hegf,
                 float* __restrict__ out)
{
    int idx = blockIdx.x * blockDim.x + threadIdx.x;   // [0, M*NB)
    out[idx] = ypart[idx] * hegf[idx & (NBASIS - 1)];
}

extern "C" void kernel_launch(void* const* d_in, const int* in_sizes, int n_in,
                              void* d_out, int out_size, void* d_ws, size_t ws_size,
                              hipStream_t stream) {
    const void* rho        = d_in[0];
    const void* gamma      = d_in[1];
    const void* coords     = d_in[2];
    const void* weights    = d_in[3];
    const void* out_coords = d_in[4];
    const void* w1         = d_in[5];
    const void* b1         = d_in[6];
    const void* w2         = d_in[7];
    const void* b2         = d_in[8];

    char* ws = (char*)d_ws;
    // ws layout (1.1253 MB total — proven mapped in R1):
    //   cw      : N * float4           = 128 KiB  @ 0
    //   betaneg : N * 16 * float       = 512 KiB  @ 128K
    //   hegf    : 17 * float (256B)               @ 640K
    //   ypart   : M * 16 * float       = 512 KiB  @ 640K + 256
    float4* cw      = (float4*)(ws);
    float*  betaneg = (float*) (ws + (128 << 10));
    float*  hegf    = (float*) (ws + (640 << 10));
    float*  ypart   = (float*) (ws + (640 << 10) + 256);

    hipMemsetAsync(ypart, 0, (size_t)M_PTS * NBASIS * sizeof(float), stream);

    cg_prep<<<N_PTS / 256, 256, 0, stream>>>(rho, gamma, coords, weights,
                                             w1, b1, w2, b2,
                                             cw, betaneg, hegf);

    dim3 grid(M_PTS / TI, N_PTS / JC);
    cg_pairs<<<grid, 256, 0, stream>>>(out_coords, cw, betaneg, hegf, ypart);

    cg_finalize<<<(M_PTS * NBASIS) / 256, 256, 0, stream>>>(ypart, hegf,
                                                            (float*)d_out);
}

// Round 8
// 397.084 us; speedup vs baseline: 1.1722x; 1.1722x over previous
//
#include <hip/hip_runtime.h>
#include <hip/hip_bf16.h>

// CoarseGraining: y[i,b] = heg[b] * sum_j exp(-beta[j,b] * d2(i,j)) * wrho[j]
// N = M = 8192, NB = 16, WIDTH = 32. Inputs float32, output float32 (proven R5).
// R5 baseline: cg_pairs 322us, VALUBusy 33% -> latency-bound on per-iter
// dependent global loads. This round: LDS-stage the j-tile, unroll, fast-math
// prep. NOTE gfx950 builtin names: exp2 = __builtin_amdgcn_exp2f,
// log2 = __builtin_amdgcn_logf (v_log_f32 is base-2; there is no _log2f).
// WS layout kept within the 1.1253 MB footprint proven in R1/R5.

#define N_PTS 8192
#define M_PTS 8192
#define NBASIS 16
#define WIDTH 32
#define TI 256      // i-points per block (== blockDim.x)
#define JC 256      // j-points per block (j-chunk tile staged in LDS)

__device__ __forceinline__ float exp2_hw(float x) { return __builtin_amdgcn_exp2f(x); }
__device__ __forceinline__ float log2_hw(float x) { return __builtin_amdgcn_logf(x); }

__device__ __forceinline__ float fast_tanh(float z) {
    float a = fabsf(z);
    float t = __expf(-2.0f * a);          // v_exp_f32
    float r = (1.0f - t) / (1.0f + t);
    return copysignf(r, z);
}

__device__ __forceinline__ float log_cosh_f(float x) {
    float a = fabsf(x);
    // log(cosh(x)) = |x| + log1p(exp(-2|x|)) - log(2);  1+q in (1,2] -> __logf fine
    return a + __logf(1.0f + __expf(-2.0f * a)) - 0.6931471805599453f;
}

// ---------------- Stage 1: per-source-point quantities ----------------
// cw[j]           = (cx, cy, cz, wrho)
// betaneg[j*16+b] = -log2(e) * beta[j,b]  (so exp(-beta*d2) = exp2(bn*d2))
// hegf[0..15]     = log_cosh(embed(0))^1.5
__global__ __launch_bounds__(256)
void cg_prep(const float* __restrict__ rho,
             const float* __restrict__ gamma,
             const float* __restrict__ coords,
             const float* __restrict__ weights,
             const float* __restrict__ w1,
             const float* __restrict__ b1,
             const float* __restrict__ w2,
             const float* __restrict__ b2,
             float4* __restrict__ cw,
             float* __restrict__ betaneg,
             float* __restrict__ hegf)
{
    const float PI_F = 3.14159265358979323846f;
    const float LOG2E = 1.4426950408889634f;

    // stage MLP weights in LDS once per block (removes 8192x redundant loads)
    __shared__ float s_w1[WIDTH], s_b1[WIDTH], s_w2[WIDTH * NBASIS], s_b2[NBASIS];
    int t = threadIdx.x;
    if (t < WIDTH) { s_w1[t] = w1[t]; s_b1[t] = b1[t]; }
    if (t < NBASIS) s_b2[t] = b2[t];
    s_w2[t] = w2[t];
    s_w2[t + 256] = w2[t + 256];
    __syncthreads();

    int j = blockIdx.x * blockDim.x + t;
    if (j < N_PTS) {
        float r = rho[j];
        float g = gamma[j];
        const float c83 = 38.28312007948569f;              // 4*(3*pi^2)^(2/3)
        float r83 = exp2_hw(2.6666666667f * log2_hw(r));   // r^(8/3)
        float s2 = g / (c83 * r83);
        float x = __logf(s2 + 1e-4f);

        float emb[NBASIS];
        #pragma unroll
        for (int b = 0; b < NBASIS; ++b) emb[b] = s_b2[b];
        #pragma unroll 4
        for (int w = 0; w < WIDTH; ++w) {
            float h = fast_tanh(fmaf(x, s_w1[w], s_b1[w]));
            #pragma unroll
            for (int b = 0; b < NBASIS; ++b)
                emb[b] = fmaf(h, s_w2[w * NBASIS + b], emb[b]);
        }
        float pref = PI_F * exp2_hw(0.6666666667f * log2_hw(0.5f * r));
        #pragma unroll
        for (int b = 0; b < NBASIS; ++b)
            betaneg[j * NBASIS + b] = -LOG2E * pref * log_cosh_f(emb[b]);

        cw[j] = make_float4(coords[j * 3 + 0],
                            coords[j * 3 + 1],
                            coords[j * 3 + 2],
                            weights[j] * r);
    }

    if (blockIdx.x == 0 && t == 0) {
        float emb0[NBASIS];
        #pragma unroll
        for (int b = 0; b < NBASIS; ++b) emb0[b] = s_b2[b];
        for (int w = 0; w < WIDTH; ++w) {
            float h = fast_tanh(s_b1[w]);   // x = 0
            #pragma unroll
            for (int b = 0; b < NBASIS; ++b)
                emb0[b] = fmaf(h, s_w2[w * NBASIS + b], emb0[b]);
        }
        #pragma unroll
        for (int b = 0; b < NBASIS; ++b) {
            float lc = fmaxf(log_cosh_f(emb0[b]), 0.0f);
            hegf[b] = lc * sqrtf(lc);       // lc^1.5
        }
    }
}

// ---------------- Stage 2: all-pairs accumulation ----------------
// grid = (M/TI, N/JC). Block stages its 256-j tile (cw 4KB + bn 16KB) in LDS
// once (coalesced float4), then the j-loop reads LDS broadcasts only.
__global__ __launch_bounds__(256, 4)
void cg_pairs(const float* __restrict__ oc,
              const float4* __restrict__ cw,
              const float4* __restrict__ bn4,   // betaneg viewed as float4[N*4]
              float* __restrict__ ypart)
{
    __shared__ float4 s_cw[JC];
    __shared__ float4 s_bn[JC * 4];

    int t = threadIdx.x;
    int j0 = blockIdx.y * JC;

    s_cw[t] = cw[j0 + t];
    #pragma unroll
    for (int q = 0; q < 4; ++q)
        s_bn[t * 4 + q] = bn4[(j0 + t) * 4 + q];

    int i = blockIdx.x * TI + t;
    float ox = oc[i * 3 + 0];
    float oy = oc[i * 3 + 1];
    float oz = oc[i * 3 + 2];

    __syncthreads();

    float acc[NBASIS];
    #pragma unroll
    for (int b = 0; b < NBASIS; ++b) acc[b] = 0.0f;

    #pragma unroll 4
    for (int j = 0; j < JC; ++j) {
        float4 c = s_cw[j];                      // LDS broadcast
        float dx = ox - c.x;
        float dy = oy - c.y;
        float dz = oz - c.z;
        float d2 = fmaf(dx, dx, fmaf(dy, dy, dz * dz));
        #pragma unroll
        for (int q = 0; q < 4; ++q) {
            float4 b4 = s_bn[j * 4 + q];         // LDS broadcast
            float e0 = exp2_hw(b4.x * d2);
            float e1 = exp2_hw(b4.y * d2);
            float e2 = exp2_hw(b4.z * d2);
            float e3 = exp2_hw(b4.w * d2);
            acc[q * 4 + 0] = fmaf(e0, c.w, acc[q * 4 + 0]);
            acc[q * 4 + 1] = fmaf(e1, c.w, acc[q * 4 + 1]);
            acc[q * 4 + 2] = fmaf(e2, c.w, acc[q * 4 + 2]);
            acc[q * 4 + 3] = fmaf(e3, c.w, acc[q * 4 + 3]);
        }
    }
    #pragma unroll
    for (int b = 0; b < NBASIS; ++b)
        atomicAdd(&ypart[i * NBASIS + b], acc[b]);
}

// ---------------- Stage 3: scale, float32 output ----------------
__global__ __launch_bounds__(256)
void cg_finalize(const float* __restrict__ ypart,
                 const float* __restrict__ hegf,
                 float* __restrict__ out)
{
    int idx = blockIdx.x * blockDim.x + threadIdx.x;   // [0, M*NB)
    out[idx] = ypart[idx] * hegf[idx & (NBASIS - 1)];
}

extern "C" void kernel_launch(void* const* d_in, const int* in_sizes, int n_in,
                              void* d_out, int out_size, void* d_ws, size_t ws_size,
                              hipStream_t stream) {
    const float* rho        = (const float*)d_in[0];
    const float* gamma      = (const float*)d_in[1];
    const float* coords     = (const float*)d_in[2];
    const float* weights    = (const float*)d_in[3];
    const float* out_coords = (const float*)d_in[4];
    const float* w1         = (const float*)d_in[5];
    const float* b1         = (const float*)d_in[6];
    const float* w2         = (const float*)d_in[7];
    const float* b2         = (const float*)d_in[8];

    char* ws = (char*)d_ws;
    // ws layout (1.1253 MB total — proven mapped in R1/R5):
    //   cw      : N * float4           = 128 KiB  @ 0
    //   betaneg : N * 16 * float       = 512 KiB  @ 128K
    //   hegf    : 16 * float (256B)               @ 640K
    //   ypart   : M * 16 * float       = 512 KiB  @ 640K + 256
    float4* cw      = (float4*)(ws);
    float*  betaneg = (float*) (ws + (128 << 10));
    float*  hegf    = (float*) (ws + (640 << 10));
    float*  ypart   = (float*) (ws + (640 << 10) + 256);

    (void)hipMemsetAsync(ypart, 0, (size_t)M_PTS * NBASIS * sizeof(float), stream);

    cg_prep<<<N_PTS / 256, 256, 0, stream>>>(rho, gamma, coords, weights,
                                             w1, b1, w2, b2,
                                             cw, betaneg, hegf);

    dim3 grid(M_PTS / TI, N_PTS / JC);
    cg_pairs<<<grid, 256, 0, stream>>>(out_coords, cw, (const float4*)betaneg,
                                       ypart);

    cg_finalize<<<(M_PTS * NBASIS) / 256, 256, 0, stream>>>(ypart, hegf,
                                                            (float*)d_out);
}